// Round 5
// baseline (7100.898 us; speedup 1.0000x reference)
//
#include <hip/hip_runtime.h>
#include <cstdint>

#define N_B 64
#define T_T 512
#define D_D 1024
#define H_H 1024
#define G4H 4096
#define NBLK 256

typedef __attribute__((ext_vector_type(8))) short short8;
typedef __attribute__((ext_vector_type(4))) float f32x4;

__device__ inline uint16_t f2bf(float f) {
    union { float f; uint32_t u; } v; v.f = f;
    uint32_t u = v.u + 0x7FFFu + ((v.u >> 16) & 1u);   // RNE
    return (uint16_t)(u >> 16);
}
__device__ inline float bf2f(uint16_t h) {
    union { uint32_t u; float f; } v; v.u = ((uint32_t)h) << 16;
    return v.f;
}
__device__ inline f32x4 mfma16(short8 a, short8 b, f32x4 c) {
    return __builtin_amdgcn_mfma_f32_16x16x32_bf16(a, b, c, 0, 0, 0);
}
__device__ inline float sigm(float x) {
    return 1.0f / (1.0f + __builtin_amdgcn_exp2f(-1.44269504f * x));
}
__device__ inline float tanh_f(float x) {
    float e = __builtin_amdgcn_exp2f(2.88539008f * x);  // e^(2x)
    return 1.0f - 2.0f / (e + 1.0f);
}
__device__ inline short8 cvt_pack(float4 u0, float4 u1) {
    short8 a;
    a[0] = (short)f2bf(u0.x); a[1] = (short)f2bf(u0.y);
    a[2] = (short)f2bf(u0.z); a[3] = (short)f2bf(u0.w);
    a[4] = (short)f2bf(u1.x); a[5] = (short)f2bf(u1.y);
    a[6] = (short)f2bf(u1.z); a[7] = (short)f2bf(u1.w);
    return a;
}
// agent-coherent 16B store: write-through to LLC (bypasses dirty-L2 path)
__device__ inline void store16_cohere(uint16_t* p, short8 v) {
    asm volatile("global_store_dwordx4 %0, %1, off sc1" :: "v"(p), "v"(v) : "memory");
}

// ---- W (1024 x 4096 fp32) -> WT (4096 x 1024 bf16) ----
__global__ __launch_bounds__(256) void transposeW(const float* __restrict__ W,
                                                  uint16_t* __restrict__ WT) {
    __shared__ float tile[32][33];
    const int tx = threadIdx.x & 31, ty = threadIdx.x >> 5;
    const int n0 = blockIdx.x * 32, k0 = blockIdx.y * 32;
#pragma unroll
    for (int yy = 0; yy < 32; yy += 8)
        tile[ty + yy][tx] = W[(size_t)(k0 + ty + yy) * G4H + n0 + tx];
    __syncthreads();
#pragma unroll
    for (int yy = 0; yy < 32; yy += 8)
        WT[(size_t)(n0 + ty + yy) * 1024 + k0 + tx] = f2bf(tile[tx][ty + yy]);
}

// ---- h0 fp32 -> bf16 buffer0, zero c/flags ----
__global__ void prep_h0(const float* __restrict__ h0, uint16_t* __restrict__ hb,
                        float* __restrict__ c) {
    int i = blockIdx.x * 256 + threadIdx.x;   // 65536 total
    hb[i] = f2bf(h0[i]);
    c[i] = 0.0f;
}

// ---- big GEMM: xW[t*64+nb][col] = x[nb][t][:] . Wx[:, col] ----
// LDS-staged, fully coalesced global loads. BM=64, BN=128, BK=64.
// Accumulation order is bitwise-identical to the previous version.
template<bool F32OUT>
__global__ __launch_bounds__(256) void xw_gemm(const float* __restrict__ x,
                                               const uint16_t* __restrict__ WxT,
                                               void* __restrict__ xWout) {
    __shared__ uint16_t ash[64 * 72];    //  9.2 KB, row stride 144B (16B-aligned)
    __shared__ uint16_t bsh[128 * 72];   // 18.4 KB
    const int tid = threadIdx.x;
    const int wv = tid >> 6, lane = tid & 63;
    const int quad = lane >> 4, r = lane & 15;
    const int t = blockIdx.y;
    const int nb = blockIdx.x * 128;
    const int n0 = nb + wv * 32;

    f32x4 acc[4][2] = {};

    for (int k0 = 0; k0 < D_D; k0 += 64) {
        __syncthreads();
        // stage A: 64 rows x 64 k fp32 -> bf16. 512 slots of 32B (2 rounds).
#pragma unroll
        for (int it = 0; it < 2; it++) {
            int slot = it * 256 + tid;
            int row = slot >> 3, l8 = slot & 7;
            const float* src = x + ((size_t)row * T_T + t) * D_D + k0 + l8 * 8;
            float4 u0 = *(const float4*)(src);
            float4 u1 = *(const float4*)(src + 4);
            *(short8*)(ash + row * 72 + l8 * 8) = cvt_pack(u0, u1);
        }
        // stage B: 128 cols x 64 k bf16. 1024 slots of 16B (4 rounds).
#pragma unroll
        for (int it = 0; it < 4; it++) {
            int slot = it * 256 + tid;
            int col = slot >> 3, l8 = slot & 7;
            short8 v = *(const short8*)(WxT + (size_t)(nb + col) * D_D + k0 + l8 * 8);
            *(short8*)(bsh + col * 72 + l8 * 8) = v;
        }
        __syncthreads();
        // compute: per wave 32 cols, 2 k-slices of 32
#pragma unroll
        for (int kk = 0; kk < 2; kk++) {
            const int ko = kk * 32 + quad * 8;
            short8 b0 = *(const short8*)(bsh + (wv * 32 + r) * 72 + ko);
            short8 b1 = *(const short8*)(bsh + (wv * 32 + 16 + r) * 72 + ko);
#pragma unroll
            for (int mt = 0; mt < 4; mt++) {
                short8 a = *(const short8*)(ash + (mt * 16 + r) * 72 + ko);
                acc[mt][0] = mfma16(a, b0, acc[mt][0]);
                acc[mt][1] = mfma16(a, b1, acc[mt][1]);
            }
        }
    }
#pragma unroll
    for (int mt = 0; mt < 4; mt++)
#pragma unroll
        for (int nt = 0; nt < 2; nt++)
#pragma unroll
            for (int i = 0; i < 4; i++) {
                size_t row = (size_t)t * 64 + mt * 16 + quad * 4 + i;
                size_t idx = row * G4H + n0 + nt * 16 + r;
                if (F32OUT) ((float*)xWout)[idx] = acc[mt][nt][i];
                else        ((uint16_t*)xWout)[idx] = f2bf(acc[mt][nt][i]);
            }
}

// ---- persistent recurrence: all 512 timesteps in one kernel ----
// 256 blocks x 256 threads, 1 block/CU. bm = m-half (32 rows), bj = 8 h-cols.
// Sync: per-block epoch flags (group = same bm). After poll: agent ACQUIRE
// fence (buffer_inv, cheap) -> plain cached h loads (hit per-XCD L2).
// h writes: LDS-gathered 16B sc1 stores (write-through to LLC), drained
// before the flag publish. out: LDS-gathered 16B plain stores.
// xW slice double-buffered in registers (prefetch t+1 during step t).
template<int MODE>   // 1 = bf16 xW, 2 = fp32 xW
__global__ __launch_bounds__(256) void lstm_persist(
    uint16_t* __restrict__ hb, const uint16_t* __restrict__ WhT,
    const void* __restrict__ xW, const float* __restrict__ bias,
    float* __restrict__ out, int* __restrict__ flags) {
    __shared__ uint16_t bsh[32768];      // 64 KB Wh slice, consumption order
    __shared__ float red[4][32 * 33];    // 16.5 KB cross-wave reduction
    __shared__ uint16_t h_st[32 * 8];    // h gather (bf16)
    __shared__ float o_st[32 * 8];       // out gather (fp32)
    const int tid = threadIdx.x;
    const int wv = tid >> 6, lane = tid & 63;
    const int quad = lane >> 4, r = lane & 15;
    const int bm = blockIdx.x & 1, bj = blockIdx.x >> 1;
    const int j0 = bj * 8, m0 = bm * 32;
    const int slot = bm * 128 + bj;

    // ---- stage WhT slice -> LDS in consumption order ----
    for (int idx = tid; idx < 4096; idx += 256) {
        int lc = idx >> 7;          // 0..31 local col
        int k8 = idx & 127;         // k/8
        int col = (lc >> 3) * H_H + j0 + (lc & 7);   // gate = lc>>3
        short8 v = *(const short8*)(WhT + (size_t)col * H_H + k8 * 8);
        int u = (((k8 >> 2) * 2 + (lc >> 4)) << 6) | ((k8 & 3) << 4) | (lc & 15);
        *(short8*)((char*)bsh + (size_t)u * 16) = v;
    }

    // epilogue ownership: mrow = tid&31, jj = tid>>5
    const int mrow = tid & 31, jj = tid >> 5;
    const int m = m0 + mrow, j = j0 + jj;
    float bias_r[4];
#pragma unroll
    for (int g = 0; g < 4; g++) bias_r[g] = bias[g * H_H + j];
    float c_reg = 0.0f;

    // preload xW slice for t = 0
    float xwc[4], xwn[4];
#pragma unroll
    for (int g = 0; g < 4; g++) {
        size_t idx = (size_t)m * G4H + (size_t)g * H_H + j;
        if (MODE == 2) xwc[g] = ((const float*)xW)[idx];
        else           xwc[g] = bf2f(((const uint16_t*)xW)[idx]);
    }

    __syncthreads();

    const char* bbase = (const char*)bsh + wv * 16384 + (size_t)lane * 16;

    for (int t = 0; t < T_T; t++) {
        // ---- wait for my m-group's h(t) ----
        if (t) {
            if (wv == 0) {
                int* fg = flags + bm * 128;
                const int i0 = lane * 2;
                for (;;) {
                    int f0 = __hip_atomic_load(fg + i0,     __ATOMIC_RELAXED, __HIP_MEMORY_SCOPE_AGENT);
                    int f1 = __hip_atomic_load(fg + i0 + 1, __ATOMIC_RELAXED, __HIP_MEMORY_SCOPE_AGENT);
                    if (__all(f0 >= t && f1 >= t)) break;
                    __builtin_amdgcn_s_sleep(1);
                }
            }
            __syncthreads();
            // acquire: invalidate L1/L2 so plain loads see LLC-fresh h
            __builtin_amdgcn_fence(__ATOMIC_ACQUIRE, "agent");
        }

        const uint16_t* hin = hb + (size_t)(t & 1) * (N_B * H_H);
        uint16_t* hout = hb + (size_t)((t + 1) & 1) * (N_B * H_H);

        // ---- h loads: plain cached (L2-hit after first touch per XCD) ----
        const uint16_t* a0p = hin + (size_t)(m0 + r) * H_H + wv * 256 + quad * 8;
        const uint16_t* a1p = a0p + (size_t)16 * H_H;
        short8 a0v[8], a1v[8];
#pragma unroll
        for (int kk = 0; kk < 8; kk++) {
            a0v[kk] = *(const short8*)(a0p + kk * 32);
            a1v[kk] = *(const short8*)(a1p + kk * 32);
        }

        // prefetch NEXT step's xW slice (independent of h; hides HBM latency)
        const int tn = (t + 1 < T_T) ? t + 1 : t;
#pragma unroll
        for (int g = 0; g < 4; g++) {
            size_t idx = ((size_t)tn * 64 + m) * G4H + (size_t)g * H_H + j;
            if (MODE == 2) xwn[g] = ((const float*)xW)[idx];
            else           xwn[g] = bf2f(((const uint16_t*)xW)[idx]);
        }

        // ---- h @ Wh : K=1024 split 4 ways across waves; B from LDS ----
        f32x4 acc[2][2] = {};
#pragma unroll
        for (int kk = 0; kk < 8; kk++) {
            short8 b0 = *(const short8*)(bbase + kk * 2048);
            short8 b1 = *(const short8*)(bbase + kk * 2048 + 1024);
            acc[0][0] = mfma16(a0v[kk], b0, acc[0][0]);
            acc[0][1] = mfma16(a0v[kk], b1, acc[0][1]);
            acc[1][0] = mfma16(a1v[kk], b0, acc[1][0]);
            acc[1][1] = mfma16(a1v[kk], b1, acc[1][1]);
        }

        // partial tiles -> LDS
#pragma unroll
        for (int mt = 0; mt < 2; mt++)
#pragma unroll
            for (int nt = 0; nt < 2; nt++)
#pragma unroll
                for (int i = 0; i < 4; i++)
                    red[wv][(mt * 16 + quad * 4 + i) * 33 + nt * 16 + r] = acc[mt][nt][i];
        __syncthreads();

        // ---- epilogue: one (m,j) per thread; xW from regs (prev prefetch) ----
        float av[4];
#pragma unroll
        for (int g = 0; g < 4; g++) {
            int idx = mrow * 33 + g * 8 + jj;
            float s = red[0][idx] + red[1][idx] + red[2][idx] + red[3][idx];
            av[g] = s + xwc[g] + bias_r[g];
        }
        float i_ = sigm(av[0]);
        float f_ = sigm(av[1]);
        float o_ = sigm(av[2]);
        float g_ = tanh_f(av[3]);
        float cn = f_ * c_reg + i_ * g_;
        c_reg = cn;
        float hn = o_ * tanh_f(cn);

        // gather into LDS for coalesced stores
        h_st[mrow * 8 + jj] = f2bf(hn);
        o_st[mrow * 8 + jj] = hn;
        __syncthreads();

        // out: 64 threads x 16B plain stores (2 per m-row, 32B/row)
        if (tid < 64) {
            int mm = tid >> 1, half = tid & 1;
            float4 ov = *(const float4*)(o_st + mm * 8 + half * 4);
            *(float4*)(out + ((size_t)(m0 + mm) * T_T + t) * H_H + j0 + half * 4) = ov;
        }
        // h: 32 threads x 16B sc1 stores (write-through to LLC)
        if (tid < 32) {
            short8 hv = *(const short8*)(h_st + tid * 8);
            store16_cohere(hout + (size_t)(m0 + tid) * H_H + j0, hv);
        }

        // drain all stores (and xwn loads), block rendezvous, publish epoch
        asm volatile("s_waitcnt vmcnt(0)" ::: "memory");
        __syncthreads();
        if (tid == 0)
            __hip_atomic_store(flags + slot, t + 1,
                               __ATOMIC_RELAXED, __HIP_MEMORY_SCOPE_AGENT);

        // rotate xW prefetch regs
#pragma unroll
        for (int g = 0; g < 4; g++) xwc[g] = xwn[g];
    }
}

// ---- one recurrence step (fallback for tiny workspace, fused) ----
__global__ __launch_bounds__(256) void lstm_step(
    const uint16_t* __restrict__ hin, uint16_t* __restrict__ hout,
    float* __restrict__ cst,
    const uint16_t* __restrict__ WhT, const uint16_t* __restrict__ WxT,
    const float* __restrict__ x,
    const float* __restrict__ bias, float* __restrict__ out, int t) {
    __shared__ float red[4][32 * 32];
    const int tid = threadIdx.x;
    const int wv = tid >> 6, lane = tid & 63;
    const int quad = lane >> 4, r = lane & 15;
    const int bm = blockIdx.x & 1, bj = blockIdx.x >> 1;
    const int j0 = bj * 8, m0 = bm * 32;

    const int colA = (r >> 3) * H_H + j0 + (r & 7);
    const int colB = (2 + (r >> 3)) * H_H + j0 + (r & 7);

    f32x4 acc[2][2] = {};

    if (wv < 2) {  // x part, K-half of 1024
        const int kb = wv * 512;
        const float* a0p = x + ((size_t)(m0 + r) * T_T + t) * D_D + kb;
        const float* a1p = x + ((size_t)(m0 + 16 + r) * T_T + t) * D_D + kb;
        const uint16_t* b0p = WxT + (size_t)colA * D_D + kb;
        const uint16_t* b1p = WxT + (size_t)colB * D_D + kb;
#pragma unroll 4
        for (int kk = 0; kk < 512; kk += 32) {
            const int k = kk + quad * 8;
            short8 b0 = *(const short8*)(b0p + k);
            short8 b1 = *(const short8*)(b1p + k);
            short8 a0 = cvt_pack(*(const float4*)(a0p + k), *(const float4*)(a0p + k + 4));
            short8 a1 = cvt_pack(*(const float4*)(a1p + k), *(const float4*)(a1p + k + 4));
            acc[0][0] = mfma16(a0, b0, acc[0][0]);
            acc[0][1] = mfma16(a0, b1, acc[0][1]);
            acc[1][0] = mfma16(a1, b0, acc[1][0]);
            acc[1][1] = mfma16(a1, b1, acc[1][1]);
        }
    } else {       // h part, K-half of 1024
        const int kb = (wv - 2) * 512;
        const uint16_t* a0p = hin + (size_t)(m0 + r) * H_H + kb;
        const uint16_t* a1p = hin + (size_t)(m0 + 16 + r) * H_H + kb;
        const uint16_t* b0p = WhT + (size_t)colA * H_H + kb;
        const uint16_t* b1p = WhT + (size_t)colB * H_H + kb;
#pragma unroll 4
        for (int kk = 0; kk < 512; kk += 32) {
            const int k = kk + quad * 8;
            short8 a0 = *(const short8*)(a0p + k);
            short8 a1 = *(const short8*)(a1p + k);
            short8 b0 = *(const short8*)(b0p + k);
            short8 b1 = *(const short8*)(b1p + k);
            acc[0][0] = mfma16(a0, b0, acc[0][0]);
            acc[0][1] = mfma16(a0, b1, acc[0][1]);
            acc[1][0] = mfma16(a1, b0, acc[1][0]);
            acc[1][1] = mfma16(a1, b1, acc[1][1]);
        }
    }

#pragma unroll
    for (int mt = 0; mt < 2; mt++)
#pragma unroll
        for (int nt = 0; nt < 2; nt++)
#pragma unroll
            for (int i = 0; i < 4; i++) {
                int row = mt * 16 + quad * 4 + i;
                int ci = nt * 16 + r;
                red[wv][row * 32 + ci] = acc[mt][nt][i];
            }
    __syncthreads();

    const int mrow = tid >> 3, jj = tid & 7;
    const int m = m0 + mrow, j = j0 + jj;
    float av[4];
#pragma unroll
    for (int g = 0; g < 4; g++) {
        int idx = mrow * 32 + g * 8 + jj;
        float s = red[0][idx] + red[1][idx] + red[2][idx] + red[3][idx];
        s += bias[g * H_H + j];
        av[g] = s;
    }
    float i_ = sigm(av[0]);
    float f_ = sigm(av[1]);
    float o_ = sigm(av[2]);
    float g_ = tanh_f(av[3]);
    float cp = cst[m * H_H + j];
    float cn = f_ * cp + i_ * g_;
    cst[m * H_H + j] = cn;
    float hn = o_ * tanh_f(cn);
    hout[m * H_H + j] = f2bf(hn);
    out[((size_t)m * T_T + t) * H_H + j] = hn;
}

extern "C" void kernel_launch(void* const* d_in, const int* in_sizes, int n_in,
                              void* d_out, int out_size, void* d_ws, size_t ws_size,
                              hipStream_t stream) {
    const float* x    = (const float*)d_in[0];
    const float* h0   = (const float*)d_in[1];
    const float* Wx   = (const float*)d_in[2];
    const float* Wh   = (const float*)d_in[3];
    const float* bias = (const float*)d_in[4];
    float* out = (float*)d_out;

    char* wsb = (char*)d_ws;
    uint16_t* WxT = (uint16_t*)(wsb + 0);            // 8 MB
    uint16_t* WhT = (uint16_t*)(wsb + 8388608);      // 8 MB
    uint16_t* hb  = (uint16_t*)(wsb + 16777216);     // 2 x 64x1024 bf16 = 256 KB
    float* cst    = (float*)(wsb + 17039360);        // 256 KB (c for mode 0; flags)
    void* xW      = (void*)(wsb + 17301504);
    const size_t base = 17301504ull;
    const size_t xw_elems = (size_t)G4H * N_B * T_T; // 134,217,728
    int* flags = (int*)cst;                          // 256 epoch flags, zeroed by prep_h0

    int mode = 0;                                    // fused fallback
    if (ws_size >= base + xw_elems * 4) mode = 2;    // fp32 xW (~554 MB)
    else if (ws_size >= base + xw_elems * 2) mode = 1; // bf16 xW (~286 MB)

    transposeW<<<dim3(128, 32), dim3(256), 0, stream>>>(Wx, WxT);
    transposeW<<<dim3(128, 32), dim3(256), 0, stream>>>(Wh, WhT);
    prep_h0<<<dim3(256), dim3(256), 0, stream>>>(h0, hb, cst);

    if (mode == 2) xw_gemm<true ><<<dim3(32, 512), dim3(256), 0, stream>>>(x, WxT, xW);
    if (mode == 1) xw_gemm<false><<<dim3(32, 512), dim3(256), 0, stream>>>(x, WxT, xW);

    if (mode == 2) {
        lstm_persist<2><<<dim3(NBLK), dim3(256), 0, stream>>>(hb, WhT, xW, bias, out, flags);
    } else if (mode == 1) {
        lstm_persist<1><<<dim3(NBLK), dim3(256), 0, stream>>>(hb, WhT, xW, bias, out, flags);
    } else {
        for (int t = 0; t < T_T; t++) {
            uint16_t* hin  = hb + (size_t)(t & 1) * (N_B * H_H);
            uint16_t* hout = hb + (size_t)((t + 1) & 1) * (N_B * H_H);
            lstm_step<<<dim3(256), dim3(256), 0, stream>>>(hin, hout, cst, WhT, WxT, x, bias, out, t);
        }
    }
}

// Round 6
// 3723.334 us; speedup vs baseline: 1.9071x; 1.9071x over previous
//
#include <hip/hip_runtime.h>
#include <cstdint>

#define N_B 64
#define T_T 512
#define D_D 1024
#define H_H 1024
#define G4H 4096
#define NBLK 256

typedef __attribute__((ext_vector_type(8))) short short8;
typedef __attribute__((ext_vector_type(4))) float f32x4;

__device__ inline uint16_t f2bf(float f) {
    union { float f; uint32_t u; } v; v.f = f;
    uint32_t u = v.u + 0x7FFFu + ((v.u >> 16) & 1u);   // RNE
    return (uint16_t)(u >> 16);
}
__device__ inline float bf2f(uint16_t h) {
    union { uint32_t u; float f; } v; v.u = ((uint32_t)h) << 16;
    return v.f;
}
__device__ inline f32x4 mfma16(short8 a, short8 b, f32x4 c) {
    return __builtin_amdgcn_mfma_f32_16x16x32_bf16(a, b, c, 0, 0, 0);
}
__device__ inline float sigm(float x) {
    return 1.0f / (1.0f + __builtin_amdgcn_exp2f(-1.44269504f * x));
}
__device__ inline float tanh_f(float x) {
    float e = __builtin_amdgcn_exp2f(2.88539008f * x);  // e^(2x)
    return 1.0f - 2.0f / (e + 1.0f);
}
__device__ inline short8 cvt_pack(float4 u0, float4 u1) {
    short8 a;
    a[0] = (short)f2bf(u0.x); a[1] = (short)f2bf(u0.y);
    a[2] = (short)f2bf(u0.z); a[3] = (short)f2bf(u0.w);
    a[4] = (short)f2bf(u1.x); a[5] = (short)f2bf(u1.y);
    a[6] = (short)f2bf(u1.z); a[7] = (short)f2bf(u1.w);
    return a;
}
// agent-coherent 16B load: bypasses L1/L2, reads coherence point (LLC)
__device__ inline short8 load16_cohere(const uint16_t* p) {
    short8 v;
    asm volatile("global_load_dwordx4 %0, %1, off sc1"
                 : "=v"(v) : "v"(p) : "memory");
    return v;
}
// agent-coherent 16B store: write-through to LLC
__device__ inline void store16_cohere(uint16_t* p, short8 v) {
    asm volatile("global_store_dwordx4 %0, %1, off sc1" :: "v"(p), "v"(v) : "memory");
}

// ---- W (1024 x 4096 fp32) -> WT (4096 x 1024 bf16) ----
__global__ __launch_bounds__(256) void transposeW(const float* __restrict__ W,
                                                  uint16_t* __restrict__ WT) {
    __shared__ float tile[32][33];
    const int tx = threadIdx.x & 31, ty = threadIdx.x >> 5;
    const int n0 = blockIdx.x * 32, k0 = blockIdx.y * 32;
#pragma unroll
    for (int yy = 0; yy < 32; yy += 8)
        tile[ty + yy][tx] = W[(size_t)(k0 + ty + yy) * G4H + n0 + tx];
    __syncthreads();
#pragma unroll
    for (int yy = 0; yy < 32; yy += 8)
        WT[(size_t)(n0 + ty + yy) * 1024 + k0 + tx] = f2bf(tile[tx][ty + yy]);
}

// ---- h0 fp32 -> bf16 buffer0, zero c/flags ----
__global__ void prep_h0(const float* __restrict__ h0, uint16_t* __restrict__ hb,
                        float* __restrict__ c) {
    int i = blockIdx.x * 256 + threadIdx.x;   // 65536 total
    hb[i] = f2bf(h0[i]);
    c[i] = 0.0f;
}

// ---- big GEMM: xW[t*64+nb][col] = x[nb][t][:] . Wx[:, col] ----
// LDS-staged, fully coalesced global loads. BM=64, BN=128, BK=64.
template<bool F32OUT>
__global__ __launch_bounds__(256) void xw_gemm(const float* __restrict__ x,
                                               const uint16_t* __restrict__ WxT,
                                               void* __restrict__ xWout) {
    __shared__ uint16_t ash[64 * 72];    //  9.2 KB, row stride 144B (16B-aligned)
    __shared__ uint16_t bsh[128 * 72];   // 18.4 KB
    const int tid = threadIdx.x;
    const int wv = tid >> 6, lane = tid & 63;
    const int quad = lane >> 4, r = lane & 15;
    const int t = blockIdx.y;
    const int nb = blockIdx.x * 128;
    const int n0 = nb + wv * 32;

    f32x4 acc[4][2] = {};

    for (int k0 = 0; k0 < D_D; k0 += 64) {
        __syncthreads();
        // stage A: 64 rows x 64 k fp32 -> bf16. 512 slots of 32B (2 rounds).
#pragma unroll
        for (int it = 0; it < 2; it++) {
            int slot = it * 256 + tid;
            int row = slot >> 3, l8 = slot & 7;
            const float* src = x + ((size_t)row * T_T + t) * D_D + k0 + l8 * 8;
            float4 u0 = *(const float4*)(src);
            float4 u1 = *(const float4*)(src + 4);
            *(short8*)(ash + row * 72 + l8 * 8) = cvt_pack(u0, u1);
        }
        // stage B: 128 cols x 64 k bf16. 1024 slots of 16B (4 rounds).
#pragma unroll
        for (int it = 0; it < 4; it++) {
            int slot = it * 256 + tid;
            int col = slot >> 3, l8 = slot & 7;
            short8 v = *(const short8*)(WxT + (size_t)(nb + col) * D_D + k0 + l8 * 8);
            *(short8*)(bsh + col * 72 + l8 * 8) = v;
        }
        __syncthreads();
        // compute: per wave 32 cols, 2 k-slices of 32
#pragma unroll
        for (int kk = 0; kk < 2; kk++) {
            const int ko = kk * 32 + quad * 8;
            short8 b0 = *(const short8*)(bsh + (wv * 32 + r) * 72 + ko);
            short8 b1 = *(const short8*)(bsh + (wv * 32 + 16 + r) * 72 + ko);
#pragma unroll
            for (int mt = 0; mt < 4; mt++) {
                short8 a = *(const short8*)(ash + (mt * 16 + r) * 72 + ko);
                acc[mt][0] = mfma16(a, b0, acc[mt][0]);
                acc[mt][1] = mfma16(a, b1, acc[mt][1]);
            }
        }
    }
#pragma unroll
    for (int mt = 0; mt < 4; mt++)
#pragma unroll
        for (int nt = 0; nt < 2; nt++)
#pragma unroll
            for (int i = 0; i < 4; i++) {
                size_t row = (size_t)t * 64 + mt * 16 + quad * 4 + i;
                size_t idx = row * G4H + n0 + nt * 16 + r;
                if (F32OUT) ((float*)xWout)[idx] = acc[mt][nt][i];
                else        ((uint16_t*)xWout)[idx] = f2bf(acc[mt][nt][i]);
            }
}

// ---- persistent recurrence: all 512 timesteps in one kernel ----
// 256 blocks x 256 threads, 1 block/CU. bm = m-half (32 rows), bj = 8 h-cols.
// Sync: per-block epoch flags. NO cache-wide fences anywhere in the loop.
// h comms: sc1 write-through 16B stores (LDS-gathered) -> sc1 direct-LLC
// 16B loads (round-2 proven path). out: LDS-gathered plain 16B stores,
// issued on a different wave than h so the pre-publish vmcnt(0) drain
// (wave-local) covers only the 32 h-stores.
// xW(t+1) prefetch issued AFTER the h-load drain so the drain never waits
// on HBM; consumed from registers next step.
template<int MODE>   // 1 = bf16 xW, 2 = fp32 xW
__global__ __launch_bounds__(256) void lstm_persist(
    uint16_t* __restrict__ hb, const uint16_t* __restrict__ WhT,
    const void* __restrict__ xW, const float* __restrict__ bias,
    float* __restrict__ out, int* __restrict__ flags) {
    __shared__ uint16_t bsh[32768];      // 64 KB Wh slice, consumption order
    __shared__ float red[4][32 * 33];    // 16.5 KB cross-wave reduction
    __shared__ uint16_t h_st[32 * 8];    // h gather (bf16)
    __shared__ float o_st[32 * 8];       // out gather (fp32)
    const int tid = threadIdx.x;
    const int wv = tid >> 6, lane = tid & 63;
    const int quad = lane >> 4, r = lane & 15;
    const int bm = blockIdx.x & 1, bj = blockIdx.x >> 1;
    const int j0 = bj * 8, m0 = bm * 32;
    const int slot = bm * 128 + bj;

    // ---- stage WhT slice -> LDS in consumption order ----
    for (int idx = tid; idx < 4096; idx += 256) {
        int lc = idx >> 7;          // 0..31 local col
        int k8 = idx & 127;         // k/8
        int col = (lc >> 3) * H_H + j0 + (lc & 7);   // gate = lc>>3
        short8 v = *(const short8*)(WhT + (size_t)col * H_H + k8 * 8);
        int u = (((k8 >> 2) * 2 + (lc >> 4)) << 6) | ((k8 & 3) << 4) | (lc & 15);
        *(short8*)((char*)bsh + (size_t)u * 16) = v;
    }

    // epilogue ownership: mrow = tid&31, jj = tid>>5
    const int mrow = tid & 31, jj = tid >> 5;
    const int m = m0 + mrow, j = j0 + jj;
    float bias_r[4];
#pragma unroll
    for (int g = 0; g < 4; g++) bias_r[g] = bias[g * H_H + j];
    float c_reg = 0.0f;

    // preload xW slice for t = 0
    float xwc[4], xwn[4];
#pragma unroll
    for (int g = 0; g < 4; g++) {
        size_t idx = (size_t)m * G4H + (size_t)g * H_H + j;
        if (MODE == 2) xwc[g] = ((const float*)xW)[idx];
        else           xwc[g] = bf2f(((const uint16_t*)xW)[idx]);
    }

    __syncthreads();

    const char* bbase = (const char*)bsh + wv * 16384 + (size_t)lane * 16;

    for (int t = 0; t < T_T; t++) {
        // ---- wait for my m-group's h(t) (epoch flags, no RMW, no fences) ----
        if (t) {
            if (wv == 0) {
                int* fg = flags + bm * 128;
                const int i0 = lane * 2;
                for (;;) {
                    int f0 = __hip_atomic_load(fg + i0,     __ATOMIC_RELAXED, __HIP_MEMORY_SCOPE_AGENT);
                    int f1 = __hip_atomic_load(fg + i0 + 1, __ATOMIC_RELAXED, __HIP_MEMORY_SCOPE_AGENT);
                    if (__all(f0 >= t && f1 >= t)) break;
                    __builtin_amdgcn_s_sleep(1);
                }
            }
            __syncthreads();
        }

        const uint16_t* hin = hb + (size_t)(t & 1) * (N_B * H_H);
        uint16_t* hout = hb + (size_t)((t + 1) & 1) * (N_B * H_H);

        // ---- coherent h loads (direct LLC; round-2 proven path) ----
        const uint16_t* a0p = hin + (size_t)(m0 + r) * H_H + wv * 256 + quad * 8;
        const uint16_t* a1p = a0p + (size_t)16 * H_H;
        short8 a0v[8], a1v[8];
#pragma unroll
        for (int kk = 0; kk < 8; kk++) {
            a0v[kk] = load16_cohere(a0p + kk * 32);
            a1v[kk] = load16_cohere(a1p + kk * 32);
        }
        asm volatile("s_waitcnt vmcnt(0)" ::: "memory");
        __builtin_amdgcn_sched_barrier(0);

        // prefetch NEXT step's xW slice (issued after the drain -> its HBM
        // latency hides under the MFMA/reduce/epilogue phases)
        const int tn = (t + 1 < T_T) ? t + 1 : t;
#pragma unroll
        for (int g = 0; g < 4; g++) {
            size_t idx = ((size_t)tn * 64 + m) * G4H + (size_t)g * H_H + j;
            if (MODE == 2) xwn[g] = ((const float*)xW)[idx];
            else           xwn[g] = bf2f(((const uint16_t*)xW)[idx]);
        }

        // ---- h @ Wh : K=1024 split 4 ways across waves; B from LDS ----
        f32x4 acc[2][2] = {};
#pragma unroll
        for (int kk = 0; kk < 8; kk++) {
            short8 b0 = *(const short8*)(bbase + kk * 2048);
            short8 b1 = *(const short8*)(bbase + kk * 2048 + 1024);
            acc[0][0] = mfma16(a0v[kk], b0, acc[0][0]);
            acc[0][1] = mfma16(a0v[kk], b1, acc[0][1]);
            acc[1][0] = mfma16(a1v[kk], b0, acc[1][0]);
            acc[1][1] = mfma16(a1v[kk], b1, acc[1][1]);
        }

        // partial tiles -> LDS
#pragma unroll
        for (int mt = 0; mt < 2; mt++)
#pragma unroll
            for (int nt = 0; nt < 2; nt++)
#pragma unroll
                for (int i = 0; i < 4; i++)
                    red[wv][(mt * 16 + quad * 4 + i) * 33 + nt * 16 + r] = acc[mt][nt][i];
        __syncthreads();

        // ---- epilogue: one (m,j) per thread; xW from regs (prev prefetch) ----
        float av[4];
#pragma unroll
        for (int g = 0; g < 4; g++) {
            int idx = mrow * 33 + g * 8 + jj;
            float s = red[0][idx] + red[1][idx] + red[2][idx] + red[3][idx];
            av[g] = s + xwc[g] + bias_r[g];
        }
        float i_ = sigm(av[0]);
        float f_ = sigm(av[1]);
        float o_ = sigm(av[2]);
        float g_ = tanh_f(av[3]);
        float cn = f_ * c_reg + i_ * g_;
        c_reg = cn;
        float hn = o_ * tanh_f(cn);

        // gather into LDS for coalesced stores
        h_st[mrow * 8 + jj] = f2bf(hn);
        o_st[mrow * 8 + jj] = hn;
        __syncthreads();

        // h: wave 0, 32 x 16B sc1 stores (write-through to LLC)
        if (tid < 32) {
            short8 hv = *(const short8*)(h_st + tid * 8);
            store16_cohere(hout + (size_t)(m0 + tid) * H_H + j0, hv);
        }
        // out: wave 2, 64 x 16B plain stores (off the publish critical path)
        if (tid >= 128 && tid < 192) {
            int q = tid - 128;
            int mm = q >> 1, half = q & 1;
            float4 ov = *(const float4*)(o_st + mm * 8 + half * 4);
            *(float4*)(out + ((size_t)(m0 + mm) * T_T + t) * H_H + j0 + half * 4) = ov;
        }
        // wave 0: drain own h stores (wave-local vmcnt), publish epoch
        if (wv == 0) {
            asm volatile("s_waitcnt vmcnt(0)" ::: "memory");
            if (tid == 0)
                __hip_atomic_store(flags + slot, t + 1,
                                   __ATOMIC_RELAXED, __HIP_MEMORY_SCOPE_AGENT);
        }

        // rotate xW prefetch regs
#pragma unroll
        for (int g = 0; g < 4; g++) xwc[g] = xwn[g];
    }
}

// ---- one recurrence step (fallback for tiny workspace, fused) ----
__global__ __launch_bounds__(256) void lstm_step(
    const uint16_t* __restrict__ hin, uint16_t* __restrict__ hout,
    float* __restrict__ cst,
    const uint16_t* __restrict__ WhT, const uint16_t* __restrict__ WxT,
    const float* __restrict__ x,
    const float* __restrict__ bias, float* __restrict__ out, int t) {
    __shared__ float red[4][32 * 32];
    const int tid = threadIdx.x;
    const int wv = tid >> 6, lane = tid & 63;
    const int quad = lane >> 4, r = lane & 15;
    const int bm = blockIdx.x & 1, bj = blockIdx.x >> 1;
    const int j0 = bj * 8, m0 = bm * 32;

    const int colA = (r >> 3) * H_H + j0 + (r & 7);
    const int colB = (2 + (r >> 3)) * H_H + j0 + (r & 7);

    f32x4 acc[2][2] = {};

    if (wv < 2) {  // x part, K-half of 1024
        const int kb = wv * 512;
        const float* a0p = x + ((size_t)(m0 + r) * T_T + t) * D_D + kb;
        const float* a1p = x + ((size_t)(m0 + 16 + r) * T_T + t) * D_D + kb;
        const uint16_t* b0p = WxT + (size_t)colA * D_D + kb;
        const uint16_t* b1p = WxT + (size_t)colB * D_D + kb;
#pragma unroll 4
        for (int kk = 0; kk < 512; kk += 32) {
            const int k = kk + quad * 8;
            short8 b0 = *(const short8*)(b0p + k);
            short8 b1 = *(const short8*)(b1p + k);
            short8 a0 = cvt_pack(*(const float4*)(a0p + k), *(const float4*)(a0p + k + 4));
            short8 a1 = cvt_pack(*(const float4*)(a1p + k), *(const float4*)(a1p + k + 4));
            acc[0][0] = mfma16(a0, b0, acc[0][0]);
            acc[0][1] = mfma16(a0, b1, acc[0][1]);
            acc[1][0] = mfma16(a1, b0, acc[1][0]);
            acc[1][1] = mfma16(a1, b1, acc[1][1]);
        }
    } else {       // h part, K-half of 1024
        const int kb = (wv - 2) * 512;
        const uint16_t* a0p = hin + (size_t)(m0 + r) * H_H + kb;
        const uint16_t* a1p = hin + (size_t)(m0 + 16 + r) * H_H + kb;
        const uint16_t* b0p = WhT + (size_t)colA * H_H + kb;
        const uint16_t* b1p = WhT + (size_t)colB * H_H + kb;
#pragma unroll 4
        for (int kk = 0; kk < 512; kk += 32) {
            const int k = kk + quad * 8;
            short8 a0 = *(const short8*)(a0p + k);
            short8 a1 = *(const short8*)(a1p + k);
            short8 b0 = *(const short8*)(b0p + k);
            short8 b1 = *(const short8*)(b1p + k);
            acc[0][0] = mfma16(a0, b0, acc[0][0]);
            acc[0][1] = mfma16(a0, b1, acc[0][1]);
            acc[1][0] = mfma16(a1, b0, acc[1][0]);
            acc[1][1] = mfma16(a1, b1, acc[1][1]);
        }
    }

#pragma unroll
    for (int mt = 0; mt < 2; mt++)
#pragma unroll
        for (int nt = 0; nt < 2; nt++)
#pragma unroll
            for (int i = 0; i < 4; i++) {
                int row = mt * 16 + quad * 4 + i;
                int ci = nt * 16 + r;
                red[wv][row * 32 + ci] = acc[mt][nt][i];
            }
    __syncthreads();

    const int mrow = tid >> 3, jj = tid & 7;
    const int m = m0 + mrow, j = j0 + jj;
    float av[4];
#pragma unroll
    for (int g = 0; g < 4; g++) {
        int idx = mrow * 32 + g * 8 + jj;
        float s = red[0][idx] + red[1][idx] + red[2][idx] + red[3][idx];
        s += bias[g * H_H + j];
        av[g] = s;
    }
    float i_ = sigm(av[0]);
    float f_ = sigm(av[1]);
    float o_ = sigm(av[2]);
    float g_ = tanh_f(av[3]);
    float cp = cst[m * H_H + j];
    float cn = f_ * cp + i_ * g_;
    cst[m * H_H + j] = cn;
    float hn = o_ * tanh_f(cn);
    hout[m * H_H + j] = f2bf(hn);
    out[((size_t)m * T_T + t) * H_H + j] = hn;
}

extern "C" void kernel_launch(void* const* d_in, const int* in_sizes, int n_in,
                              void* d_out, int out_size, void* d_ws, size_t ws_size,
                              hipStream_t stream) {
    const float* x    = (const float*)d_in[0];
    const float* h0   = (const float*)d_in[1];
    const float* Wx   = (const float*)d_in[2];
    const float* Wh   = (const float*)d_in[3];
    const float* bias = (const float*)d_in[4];
    float* out = (float*)d_out;

    char* wsb = (char*)d_ws;
    uint16_t* WxT = (uint16_t*)(wsb + 0);            // 8 MB
    uint16_t* WhT = (uint16_t*)(wsb + 8388608);      // 8 MB
    uint16_t* hb  = (uint16_t*)(wsb + 16777216);     // 2 x 64x1024 bf16 = 256 KB
    float* cst    = (float*)(wsb + 17039360);        // 256 KB (c for mode 0; flags)
    void* xW      = (void*)(wsb + 17301504);
    const size_t base = 17301504ull;
    const size_t xw_elems = (size_t)G4H * N_B * T_T; // 134,217,728
    int* flags = (int*)cst;                          // 256 epoch flags, zeroed by prep_h0

    int mode = 0;                                    // fused fallback
    if (ws_size >= base + xw_elems * 4) mode = 2;    // fp32 xW (~554 MB)
    else if (ws_size >= base + xw_elems * 2) mode = 1; // bf16 xW (~286 MB)

    transposeW<<<dim3(128, 32), dim3(256), 0, stream>>>(Wx, WxT);
    transposeW<<<dim3(128, 32), dim3(256), 0, stream>>>(Wh, WhT);
    prep_h0<<<dim3(256), dim3(256), 0, stream>>>(h0, hb, cst);

    if (mode == 2) xw_gemm<true ><<<dim3(32, 512), dim3(256), 0, stream>>>(x, WxT, xW);
    if (mode == 1) xw_gemm<false><<<dim3(32, 512), dim3(256), 0, stream>>>(x, WxT, xW);

    if (mode == 2) {
        lstm_persist<2><<<dim3(NBLK), dim3(256), 0, stream>>>(hb, WhT, xW, bias, out, flags);
    } else if (mode == 1) {
        lstm_persist<1><<<dim3(NBLK), dim3(256), 0, stream>>>(hb, WhT, xW, bias, out, flags);
    } else {
        for (int t = 0; t < T_T; t++) {
            uint16_t* hin  = hb + (size_t)(t & 1) * (N_B * H_H);
            uint16_t* hout = hb + (size_t)((t + 1) & 1) * (N_B * H_H);
            lstm_step<<<dim3(256), dim3(256), 0, stream>>>(hin, hout, cst, WhT, WxT, x, bias, out, t);
        }
    }
}